// Round 10
// baseline (254.041 us; speedup 1.0000x reference)
//
#include <hip/hip_runtime.h>
#include <cstdint>

typedef unsigned short u16;
typedef unsigned int   u32;
typedef __attribute__((ext_vector_type(8))) short  short8;
typedef __attribute__((ext_vector_type(4))) float  floatx4;

#define NPTS 524288   // B*N2*K

__device__ __forceinline__ float b2f(u16 h) { return __uint_as_float(((u32)h) << 16); }
__device__ __forceinline__ u16 f2b(float f) {
  u32 u = __float_as_uint(f);
  return (u16)((u + 0x7FFFu + ((u >> 16) & 1u)) >> 16);
}
__device__ __forceinline__ u32 pk_bf16(float lo, float hi) {
  return (u32)f2b(lo) | ((u32)f2b(hi) << 16);
}
__device__ __forceinline__ short8 ld_frag8(const u16* p) {
  union { uint4 q; short8 s; } x;
  x.q = *(const uint4*)p;
  return x.s;
}
// barrier that drains ONLY LDS ops — global loads/stores stay in flight
__device__ __forceinline__ void bar_lds() {
  asm volatile("s_waitcnt lgkmcnt(0)\n\ts_barrier" ::: "memory");
}

// ---- combined prep: featT transpose + dxyz (recentred xyz, packed bf16) + W->bf16 ----
// Wb layout (u16): W0 64 x pitch104 @0 (cols 67..103 zero) ; W1 64 x pitch72 @6656 ; W2 128 x pitch72 @11264
__global__ __launch_bounds__(256) void prep_all(const float* __restrict__ inf,
                                                const float* __restrict__ ixyz,
                                                const float* __restrict__ oxyz,
                                                const int* __restrict__ nbr,
                                                const float* __restrict__ W0,
                                                const float* __restrict__ W1,
                                                const float* __restrict__ W2,
                                                u16* __restrict__ featT,
                                                uint2* __restrict__ dxyz,
                                                u16* __restrict__ Wb,
                                                u32* __restrict__ cnt,
                                                float* __restrict__ accz) {
  __shared__ float tile[32 * 33];
  const int bk = blockIdx.x, t = threadIdx.x;
  if (bk < 4096) {          // in_feature [b][c][n] f32 -> featT [b][n][c] bf16
    int b = bk >> 8, rem = bk & 255, cc = rem >> 7, nc = rem & 127;
    #pragma unroll
    for (int i = 0; i < 4; ++i) {
      int flat = t + i * 256;
      int cl = flat >> 5, nl = flat & 31;
      tile[cl * 33 + nl] = inf[(size_t)((b * 64) + cc * 32 + cl) * 4096 + nc * 32 + nl];
    }
    __syncthreads();
    #pragma unroll
    for (int i = 0; i < 4; ++i) {
      int flat = t + i * 256;
      int nl = flat >> 5, cl = flat & 31;
      featT[(size_t)((b << 12) + nc * 32 + nl) * 64 + cc * 32 + cl] = f2b(tile[cl * 33 + nl]);
    }
  } else if (bk < 6144) {   // dxyz[P] = in_xyz[nbr[P]] - out_xyz[n2], packed bf16 (dx,dy | dz,0)
    int g = (bk - 4096) * 256 + t;      // 0..524287
    int b = g >> 15, r = g & 32767, n2 = r >> 5;
    int id = nbr[g];
    const float* ix = ixyz + (size_t)b * 12288;
    const float* ox = oxyz + (size_t)b * 3072;
    float dx = ix[id]        - ox[n2];
    float dy = ix[4096 + id] - ox[1024 + n2];
    float dzv = ix[8192 + id] - ox[2048 + n2];
    dxyz[g] = make_uint2(pk_bf16(dx, dy), pk_bf16(dzv, 0.f));
  } else {                  // weights: 20480 u16 over 80 blocks + counter/acc zeroing
    int s = (bk - 6144) * 256 + t;
    u16 v = 0;
    if (s < 6656)       { int o = s / 104, c = s % 104; if (c < 67) v = f2b(W0[o * 67 + c]); }
    else if (s < 11264) { int q = s - 6656;  int o = q / 72, c = q % 72; if (c < 64) v = f2b(W1[o * 64 + c]); }
    else                { int q = s - 11264; int o = q / 72, c = q % 72; if (c < 64) v = f2b(W2[o * 64 + c]); }
    Wb[s] = v;
    if (bk == 6144) {
      if (t < 4) cnt[t] = 0u;
      accz[t] = 0.f;
      accz[256 + t] = 0.f;
    }
  }
}

// ---- main fused layer: 256 rows/block, dbuf LDS x-tile, W in regs, 3-deep issue ----
template<int KSTEPS, int OCH, bool GATHER, bool MAXOUT>
__global__ __launch_bounds__(256, 4) void gemm_layer(
    const u16* __restrict__ xsrc, const uint2* __restrict__ dxyz,
    const int* __restrict__ nbr,
    const u16* __restrict__ Wb, const float* __restrict__ ssin,
    u16* __restrict__ yout, u32* __restrict__ gm,
    float* __restrict__ partial) {
  constexpr int PITCH = KSTEPS * 32 + 8;   // 104 / 72: <=2-way LDS aliasing
  __shared__ __align__(16) u16 xs[2][64 * PITCH];
  __shared__ float red[512];
  __shared__ float ss[GATHER ? 4 : 128];

  const int t = threadIdx.x, blk = blockIdx.x;
  const int lane = t & 63, wv = t >> 6, lr = lane & 15, quad = lane >> 4;
  const int m = t >> 2, s4 = t & 3;
  const int P0 = blk * 256;
  const int b = blk >> 7;
  const int rg = wv >> 1, cg = wv & 1;   // MAXOUT wave mapping

  // W fragments -> registers (global is L2-resident; rows padded to PITCH)
  short8 wf[4][KSTEPS];
  #pragma unroll
  for (int nt = 0; nt < 4; ++nt) {
    const int orow = (MAXOUT ? cg * 64 : 0) + nt * 16 + lr;
    const u16* wr = Wb + orow * PITCH + quad * 8;
    #pragma unroll
    for (int ks = 0; ks < KSTEPS; ++ks)
      wf[nt][ks] = ld_frag8(wr + ks * 32);
  }

  if constexpr (!GATHER) {
    if (t < 128) ss[t] = ssin[t];
  }
  if constexpr (GATHER) {   // zero-pad x cols 68..103 in BOTH buffers (64..67 come from dxyz)
    #pragma unroll
    for (int bu = 0; bu < 2; ++bu) {
      if (s4 == 1) {
        u16* xr = xs[bu] + m * PITCH;
        #pragma unroll
        for (int j = 0; j < 9; ++j) *(uint2*)(xr + 68 + j * 4) = make_uint2(0u, 0u);
      }
    }
  }
  if constexpr (!GATHER) __syncthreads();   // ss visible before commit uses it

  int idx4[4];
  if constexpr (GATHER) {
    #pragma unroll
    for (int sub = 0; sub < 4; ++sub) idx4[sub] = nbr[P0 + sub * 64 + m];
  }

  uint4 f0[3], f1[3];
  uint2 dz[3];

  auto issue = [&](int sub, int st) {   // global -> regs (stage, set st)
    const int P = P0 + sub * 64 + m;
    if constexpr (GATHER) {
      const int id = idx4[sub];
      const u16* row = xsrc + ((size_t)((b << 12) + id)) * 64;
      f0[st] = *(const uint4*)(row + s4 * 16);
      f1[st] = *(const uint4*)(row + s4 * 16 + 8);
      if (s4 == 0) dz[st] = dxyz[P];
    } else {
      const u16* row = xsrc + ((size_t)P << 6);
      f0[st] = *(const uint4*)(row + s4 * 16);
      f1[st] = *(const uint4*)(row + s4 * 16 + 8);
    }
  };

  auto commit = [&](int bu, int st) {   // regs -> LDS (BN+ReLU repack for !GATHER)
    u16* xrow = xs[bu] + m * PITCH + s4 * 16;
    if constexpr (GATHER) {
      *(uint4*)(xrow + 0) = f0[st];
      *(uint4*)(xrow + 8) = f1[st];
      if (s4 == 0) *(uint2*)(xs[bu] + m * PITCH + 64) = dz[st];   // cols 64..67 (67 = 0)
    } else {
      u32 w[8] = { f0[st].x, f0[st].y, f0[st].z, f0[st].w,
                   f1[st].x, f1[st].y, f1[st].z, f1[st].w };
      u32 o[8];
      #pragma unroll
      for (int i = 0; i < 8; ++i) {
        const int c = s4 * 16 + i * 2;
        float lo = fmaxf(b2f((u16)(w[i] & 0xffffu)) * ss[c]     + ss[64 + c],     0.f);
        float hi = fmaxf(b2f((u16)(w[i] >> 16))     * ss[c + 1] + ss[64 + c + 1], 0.f);
        o[i] = pk_bf16(lo, hi);
      }
      *(uint4*)(xrow + 0) = make_uint4(o[0], o[1], o[2], o[3]);
      *(uint4*)(xrow + 8) = make_uint4(o[4], o[5], o[6], o[7]);
    }
  };

  // 3-deep pipeline: all 4 subs' loads issued before the main loop
  issue(0, 0); issue(1, 1); issue(2, 2);
  commit(0, 0);
  issue(3, 0);
  __syncthreads();   // buf0 (+pads) visible

  float s1[4] = {0.f, 0.f, 0.f, 0.f}, s2[4] = {0.f, 0.f, 0.f, 0.f};
  u32* yo = (u32*)yout;

  #pragma unroll
  for (int sub = 0; sub < 4; ++sub) {
    const int cur = sub & 1;
    if (sub < 3) commit(cur ^ 1, (sub + 1) % 3);   // data issued >=2 iterations ago

    if constexpr (!MAXOUT) {
      const u16* ap = xs[cur] + (wv * 16 + lr) * PITCH + quad * 8;
      floatx4 acc[4];
      #pragma unroll
      for (int nt = 0; nt < 4; ++nt) acc[nt] = (floatx4){0.f, 0.f, 0.f, 0.f};
      #pragma unroll
      for (int ks = 0; ks < KSTEPS; ++ks) {
        short8 av = ld_frag8(ap + ks * 32);
        #pragma unroll
        for (int nt = 0; nt < 4; ++nt)
          acc[nt] = __builtin_amdgcn_mfma_f32_16x16x32_bf16(av, wf[nt][ks], acc[nt], 0, 0, 0);
      }
      const int R0 = P0 + sub * 64 + wv * 16 + quad * 4;
      #pragma unroll
      for (int nt = 0; nt < 4; ++nt) {
        #pragma unroll
        for (int r = 0; r < 4; ++r) {
          float v = acc[nt][r];
          s1[nt] += v; s2[nt] += v * v;
          float vo = __shfl_xor(v, 1);
          if ((lr & 1) == 0)
            yo[(size_t)(R0 + r) * 32 + nt * 8 + (lr >> 1)] = pk_bf16(v, vo);
        }
      }
    } else {
      // wave = 32 rows (rg) x 64 chans (cg): max-group fully in-wave
      short8 av[2][KSTEPS];
      #pragma unroll
      for (int h = 0; h < 2; ++h)
        #pragma unroll
        for (int ks = 0; ks < KSTEPS; ++ks)
          av[h][ks] = ld_frag8(xs[cur] + (rg * 32 + h * 16 + lr) * PITCH + quad * 8 + ks * 32);
      floatx4 acc[2][4];
      #pragma unroll
      for (int h = 0; h < 2; ++h)
        #pragma unroll
        for (int nt = 0; nt < 4; ++nt) acc[h][nt] = (floatx4){0.f, 0.f, 0.f, 0.f};
      #pragma unroll
      for (int ks = 0; ks < KSTEPS; ++ks)
        #pragma unroll
        for (int nt = 0; nt < 4; ++nt)
          #pragma unroll
          for (int h = 0; h < 2; ++h)
            acc[h][nt] = __builtin_amdgcn_mfma_f32_16x16x32_bf16(av[h][ks], wf[nt][ks], acc[h][nt], 0, 0, 0);
      float mx[4], mn[4];
      #pragma unroll
      for (int nt = 0; nt < 4; ++nt) {
        mx[nt] = -INFINITY; mn[nt] = INFINITY;
        #pragma unroll
        for (int h = 0; h < 2; ++h)
          #pragma unroll
          for (int r = 0; r < 4; ++r) {
            float v = acc[h][nt][r];
            s1[nt] += v; s2[nt] += v * v;
            mx[nt] = fmaxf(mx[nt], v); mn[nt] = fminf(mn[nt], v);
          }
        mx[nt] = fmaxf(mx[nt], __shfl_xor(mx[nt], 16));
        mx[nt] = fmaxf(mx[nt], __shfl_xor(mx[nt], 32));
        mn[nt] = fminf(mn[nt], __shfl_xor(mn[nt], 16));
        mn[nt] = fminf(mn[nt], __shfl_xor(mn[nt], 32));
      }
      if (lane < 16) {
        const int grp = blk * 8 + sub * 2 + rg;   // b*1024 + n2
        #pragma unroll
        for (int nt = 0; nt < 4; ++nt)
          gm[(size_t)grp * 128 + cg * 64 + nt * 16 + lr] = pk_bf16(mx[nt], mn[nt]);
      }
    }
    if (sub < 3) bar_lds();   // LDS-only barrier: vmem stays in flight
  }

  // block stats: shuffle over quads, LDS over waves, single barrier
  #pragma unroll
  for (int nt = 0; nt < 4; ++nt) {
    s1[nt] += __shfl_xor(s1[nt], 16); s1[nt] += __shfl_xor(s1[nt], 32);
    s2[nt] += __shfl_xor(s2[nt], 16); s2[nt] += __shfl_xor(s2[nt], 32);
  }
  if (lane < 16) {
    #pragma unroll
    for (int nt = 0; nt < 4; ++nt) {
      red[wv * 64 + nt * 16 + lr] = s1[nt];
      red[256 + wv * 64 + nt * 16 + lr] = s2[nt];
    }
  }
  __syncthreads();
  if constexpr (!MAXOUT) {
    if (t < 64) {
      partial[(size_t)blk * 128 + t] = red[t] + red[64 + t] + red[128 + t] + red[192 + t];
    } else if (t < 128) {
      int c = t - 64;
      partial[(size_t)blk * 128 + t] = red[256 + c] + red[320 + c] + red[384 + c] + red[448 + c];
    }
  } else {
    if (t < 128) {
      int half = t >> 6, i = t & 63;
      partial[(size_t)blk * 256 + t] = red[half * 64 + i] + red[(half + 2) * 64 + i];
    } else {
      int c = t - 128, half = c >> 6, i = c & 63;
      partial[(size_t)blk * 256 + t] = red[256 + half * 64 + i] + red[256 + (half + 2) * 64 + i];
    }
  }
}

// ---- merged stats: 64 blocks; atomic accumulate; last block finalizes scale/shift ----
__global__ __launch_bounds__(256) void bn_stats(const float* __restrict__ partial,
                                                float* __restrict__ accv,
                                                const float* __restrict__ gam,
                                                const float* __restrict__ bet,
                                                float* __restrict__ ssout,
                                                u32* __restrict__ counter, int och) {
  __shared__ float l[256];
  __shared__ u32 rank;
  const int cols = 2 * och, t = threadIdx.x;
  if (t < cols) {
    const size_t r0 = (size_t)blockIdx.x * 32;
    float s = 0.f;
    for (int r = 0; r < 32; ++r) s += partial[(r0 + r) * cols + t];
    atomicAdd(&accv[t], s);
  }
  __threadfence();
  __syncthreads();
  if (t == 0) rank = atomicAdd(counter, 1u);
  __syncthreads();
  if (rank != 63) return;
  __threadfence();
  if (t < cols) l[t] = accv[t];
  __syncthreads();
  if (t < och) {
    const float invN = 1.f / (float)NPTS;
    float mean = l[t] * invN;
    float var  = fmaxf(l[och + t] * invN - mean * mean, 0.f);
    float scale = gam[t] * rsqrtf(var + 1e-5f);
    ssout[t] = scale;
    ssout[och + t] = bet[t] - mean * scale;
  }
}

// ---- final: BN2 + relu on packed max/min, transpose to [b][c][n2] ----
__global__ __launch_bounds__(256) void final_out(const u32* __restrict__ gm,
                                                 const float* __restrict__ ss2,
                                                 float* __restrict__ out) {
  __shared__ float tile[64 * 33];
  int blk = blockIdx.x;                 // 1024 = 16 * 4 * 16
  int b = blk >> 6, rem = blk & 63, cc = rem >> 4, nn = rem & 15;
  int t = threadIdx.x;
  #pragma unroll
  for (int i = 0; i < 8; ++i) {
    int flat = t + i * 256;             // 2048
    int n2l = flat >> 5, cl = flat & 31;
    int c = cc * 32 + cl;
    size_t idx = (size_t)((b << 10) + nn * 64 + n2l) * 128 + c;
    u32 p = gm[idx];
    float mx = b2f((u16)(p & 0xffffu)), mn = b2f((u16)(p >> 16));
    float scv = ss2[c], shv = ss2[128 + c];
    float v = (scv >= 0.f) ? mx : mn;
    tile[n2l * 33 + cl] = fmaxf(scv * v + shv, 0.f);
  }
  __syncthreads();
  #pragma unroll
  for (int i = 0; i < 8; ++i) {
    int flat = t + i * 256;
    int cl = flat >> 6, n2l = flat & 63;
    out[(size_t)((b * 128) + cc * 32 + cl) * 1024 + nn * 64 + n2l] = tile[n2l * 33 + cl];
  }
}

extern "C" void kernel_launch(void* const* d_in, const int* in_sizes, int n_in,
                              void* d_out, int out_size, void* d_ws, size_t ws_size,
                              hipStream_t stream) {
  const float* in_xyz  = (const float*)d_in[0];
  const float* out_xyz = (const float*)d_in[1];
  const float* in_feat = (const float*)d_in[2];
  const int*   nbr     = (const int*)d_in[3];
  const float* W0 = (const float*)d_in[4];
  const float* g0 = (const float*)d_in[5];
  const float* b0 = (const float*)d_in[6];
  const float* W1 = (const float*)d_in[7];
  const float* g1 = (const float*)d_in[8];
  const float* b1 = (const float*)d_in[9];
  const float* W2 = (const float*)d_in[10];
  const float* g2 = (const float*)d_in[11];
  const float* b2 = (const float*)d_in[12];
  float* out = (float*)d_out;

  char* ws = (char*)d_ws;
  float*  ssbuf = (float*)(ws + 0);            // 768 f32
  u32*    cnt   = (u32*)(ws + 3072);           // 4 u32
  float*  accv  = (float*)(ws + 3584);         // 512 f32 (zones: +0 /+128 /+256)
  u16*    Wb    = (u16*)(ws + 8192);           // 20480 u16
  u16*    featT = (u16*)(ws + 262144);         // 8 MiB
  uint2*  dxyz  = (uint2*)(ws + 8650752);      // 4 MiB
  u16*    y0    = (u16*)(ws + 13631488);       // 64 MiB
  u16*    y1    = (u16*)(ws + 80740352);       // 64 MiB (end 147,849,216)
  // aliased into dead regions:
  float*  p0    = (float*)(ws + 80740352);     // y1 area; consumed before y1 written
  float*  p1    = (float*)(ws + 262144);       // featT area; featT dead after L0
  u32*    gm    = (u32*)(ws + 13631488);       // y0 area; y0 dead after L1 (8 MiB packed)
  float*  p2    = (float*)(ws + 13631488 + 8388608);         // 2 MiB

  hipLaunchKernelGGL(prep_all, dim3(6224), dim3(256), 0, stream,
                     in_feat, in_xyz, out_xyz, nbr, W0, W1, W2, featT, dxyz, Wb, cnt, accv);

  hipLaunchKernelGGL((gemm_layer<3, 64, true, false>), dim3(2048), dim3(256), 0, stream,
                     featT, dxyz, nbr, Wb, nullptr, y0, nullptr, p0);
  hipLaunchKernelGGL(bn_stats, dim3(64), dim3(256), 0, stream,
                     p0, accv, g0, b0, ssbuf, cnt, 64);

  hipLaunchKernelGGL((gemm_layer<2, 64, false, false>), dim3(2048), dim3(256), 0, stream,
                     y0, nullptr, nullptr, Wb + 6656, ssbuf, y1, nullptr, p1);
  hipLaunchKernelGGL(bn_stats, dim3(64), dim3(256), 0, stream,
                     p1, accv + 128, g1, b1, ssbuf + 256, cnt + 1, 64);

  hipLaunchKernelGGL((gemm_layer<2, 128, false, true>), dim3(2048), dim3(256), 0, stream,
                     y1, nullptr, nullptr, Wb + 11264, ssbuf + 256, nullptr, gm, p2);
  hipLaunchKernelGGL(bn_stats, dim3(64), dim3(256), 0, stream,
                     p2, accv + 256, g2, b2, ssbuf + 512, cnt + 2, 128);

  hipLaunchKernelGGL(final_out, dim3(1024), dim3(256), 0, stream, gm, ssbuf + 512, out);
}

// Round 11
// 214.161 us; speedup vs baseline: 1.1862x; 1.1862x over previous
//
#include <hip/hip_runtime.h>
#include <cstdint>

typedef unsigned short u16;
typedef unsigned int   u32;
typedef __attribute__((ext_vector_type(8))) short  short8;
typedef __attribute__((ext_vector_type(4))) float  floatx4;

#define NPTS 524288   // B*N2*K

__device__ __forceinline__ float b2f(u16 h) { return __uint_as_float(((u32)h) << 16); }
__device__ __forceinline__ u16 f2b(float f) {
  u32 u = __float_as_uint(f);
  return (u16)((u + 0x7FFFu + ((u >> 16) & 1u)) >> 16);
}
__device__ __forceinline__ u32 pk_bf16(float lo, float hi) {
  return (u32)f2b(lo) | ((u32)f2b(hi) << 16);
}
__device__ __forceinline__ short8 ld_frag8(const u16* p) {
  union { uint4 q; short8 s; } x;
  x.q = *(const uint4*)p;
  return x.s;
}
// barrier that drains ONLY LDS ops — global loads/stores stay in flight
__device__ __forceinline__ void bar_lds() {
  asm volatile("s_waitcnt lgkmcnt(0)\n\ts_barrier" ::: "memory");
}

// ---- combined prep: featT transpose + dxyz (recentred xyz, packed bf16) + W->bf16 ----
// Wb layout (u16): W0 64 x pitch104 @0 (cols 67..103 zero) ; W1 64 x pitch72 @6656 ; W2 128 x pitch72 @11264
__global__ __launch_bounds__(256) void prep_all(const float* __restrict__ inf,
                                                const float* __restrict__ ixyz,
                                                const float* __restrict__ oxyz,
                                                const int* __restrict__ nbr,
                                                const float* __restrict__ W0,
                                                const float* __restrict__ W1,
                                                const float* __restrict__ W2,
                                                u16* __restrict__ featT,
                                                uint2* __restrict__ dxyz,
                                                u16* __restrict__ Wb,
                                                u32* __restrict__ cnt,
                                                float* __restrict__ accz) {
  __shared__ float tile[32 * 33];
  const int bk = blockIdx.x, t = threadIdx.x;
  if (bk < 4096) {          // in_feature [b][c][n] f32 -> featT [b][n][c] bf16
    int b = bk >> 8, rem = bk & 255, cc = rem >> 7, nc = rem & 127;
    #pragma unroll
    for (int i = 0; i < 4; ++i) {
      int flat = t + i * 256;
      int cl = flat >> 5, nl = flat & 31;
      tile[cl * 33 + nl] = inf[(size_t)((b * 64) + cc * 32 + cl) * 4096 + nc * 32 + nl];
    }
    __syncthreads();
    #pragma unroll
    for (int i = 0; i < 4; ++i) {
      int flat = t + i * 256;
      int nl = flat >> 5, cl = flat & 31;
      featT[(size_t)((b << 12) + nc * 32 + nl) * 64 + cc * 32 + cl] = f2b(tile[cl * 33 + nl]);
    }
  } else if (bk < 6144) {   // dxyz[P] = in_xyz[nbr[P]] - out_xyz[n2], packed bf16 (dx,dy | dz,0)
    int g = (bk - 4096) * 256 + t;      // 0..524287
    int b = g >> 15, r = g & 32767, n2 = r >> 5;
    int id = nbr[g];
    const float* ix = ixyz + (size_t)b * 12288;
    const float* ox = oxyz + (size_t)b * 3072;
    float dx = ix[id]        - ox[n2];
    float dy = ix[4096 + id] - ox[1024 + n2];
    float dzv = ix[8192 + id] - ox[2048 + n2];
    dxyz[g] = make_uint2(pk_bf16(dx, dy), pk_bf16(dzv, 0.f));
  } else {                  // weights: 20480 u16 over 80 blocks + counter/acc zeroing
    int s = (bk - 6144) * 256 + t;
    u16 v = 0;
    if (s < 6656)       { int o = s / 104, c = s % 104; if (c < 67) v = f2b(W0[o * 67 + c]); }
    else if (s < 11264) { int q = s - 6656;  int o = q / 72, c = q % 72; if (c < 64) v = f2b(W1[o * 64 + c]); }
    else                { int q = s - 11264; int o = q / 72, c = q % 72; if (c < 64) v = f2b(W2[o * 64 + c]); }
    Wb[s] = v;
    if (bk == 6144) {
      if (t < 4) cnt[t] = 0u;
      accz[t] = 0.f;
      accz[256 + t] = 0.f;
    }
  }
}

// ---- main fused layer: 256 rows/block, dbuf LDS x-tile, W in regs, 2-deep issue ----
template<int KSTEPS, int OCH, bool GATHER, bool MAXOUT>
__global__ __launch_bounds__(256, 4) void gemm_layer(
    const u16* __restrict__ xsrc, const uint2* __restrict__ dxyz,
    const int* __restrict__ nbr,
    const u16* __restrict__ Wb, const float* __restrict__ ssin,
    u16* __restrict__ yout, u32* __restrict__ gm,
    float* __restrict__ partial) {
  constexpr int PITCH = KSTEPS * 32 + 8;   // 104 / 72: <=2-way LDS aliasing
  __shared__ __align__(16) u16 xs[2][64 * PITCH];
  __shared__ float red[512];
  __shared__ float ss[GATHER ? 4 : 128];

  const int t = threadIdx.x, blk = blockIdx.x;
  const int lane = t & 63, wv = t >> 6, lr = lane & 15, quad = lane >> 4;
  const int m = t >> 2, s4 = t & 3;
  const int P0 = blk * 256;
  const int b = blk >> 7;
  const int rg = wv >> 1, cg = wv & 1;   // MAXOUT wave mapping

  // W fragments -> registers (global is L2-resident; rows padded to PITCH)
  short8 wf[4][KSTEPS];
  #pragma unroll
  for (int nt = 0; nt < 4; ++nt) {
    const int orow = (MAXOUT ? cg * 64 : 0) + nt * 16 + lr;
    const u16* wr = Wb + orow * PITCH + quad * 8;
    #pragma unroll
    for (int ks = 0; ks < KSTEPS; ++ks)
      wf[nt][ks] = ld_frag8(wr + ks * 32);
  }

  if constexpr (!GATHER) {
    if (t < 128) ss[t] = ssin[t];
  }
  if constexpr (GATHER) {   // zero-pad x cols 68..103 in BOTH buffers (64..67 come from dxyz)
    #pragma unroll
    for (int bu = 0; bu < 2; ++bu) {
      if (s4 == 1) {
        u16* xr = xs[bu] + m * PITCH;
        #pragma unroll
        for (int j = 0; j < 9; ++j) *(uint2*)(xr + 68 + j * 4) = make_uint2(0u, 0u);
      }
    }
  }
  if constexpr (!GATHER) __syncthreads();   // ss visible before commit uses it

  int idx4[4];
  if constexpr (GATHER) {
    #pragma unroll
    for (int sub = 0; sub < 4; ++sub) idx4[sub] = nbr[P0 + sub * 64 + m];
  }

  uint4 f0, f1;
  uint2 dz = make_uint2(0u, 0u);

  auto issue = [&](int sub) {   // global -> regs (stage)
    const int P = P0 + sub * 64 + m;
    if constexpr (GATHER) {
      const int id = idx4[sub];
      const u16* row = xsrc + ((size_t)((b << 12) + id)) * 64;
      f0 = *(const uint4*)(row + s4 * 16);
      f1 = *(const uint4*)(row + s4 * 16 + 8);
      if (s4 == 0) dz = dxyz[P];
    } else {
      const u16* row = xsrc + ((size_t)P << 6);
      f0 = *(const uint4*)(row + s4 * 16);
      f1 = *(const uint4*)(row + s4 * 16 + 8);
    }
  };

  auto commit = [&](int bu) {   // regs -> LDS (BN+ReLU repack for !GATHER)
    u16* xrow = xs[bu] + m * PITCH + s4 * 16;
    if constexpr (GATHER) {
      *(uint4*)(xrow + 0) = f0;
      *(uint4*)(xrow + 8) = f1;
      if (s4 == 0) *(uint2*)(xs[bu] + m * PITCH + 64) = dz;   // cols 64..67 (67 = 0)
    } else {
      u32 w[8] = { f0.x, f0.y, f0.z, f0.w, f1.x, f1.y, f1.z, f1.w };
      u32 o[8];
      #pragma unroll
      for (int i = 0; i < 8; ++i) {
        const int c = s4 * 16 + i * 2;
        float lo = fmaxf(b2f((u16)(w[i] & 0xffffu)) * ss[c]     + ss[64 + c],     0.f);
        float hi = fmaxf(b2f((u16)(w[i] >> 16))     * ss[c + 1] + ss[64 + c + 1], 0.f);
        o[i] = pk_bf16(lo, hi);
      }
      *(uint4*)(xrow + 0) = make_uint4(o[0], o[1], o[2], o[3]);
      *(uint4*)(xrow + 8) = make_uint4(o[4], o[5], o[6], o[7]);
    }
  };

  issue(0); commit(0);
  issue(1);
  __syncthreads();   // buf0 (+pads) visible

  float s1[4] = {0.f, 0.f, 0.f, 0.f}, s2[4] = {0.f, 0.f, 0.f, 0.f};
  u32* yo = (u32*)yout;

  for (int sub = 0; sub < 4; ++sub) {
    const int cur = sub & 1;
    if (sub < 3) commit(cur ^ 1);   // prev-iter barrier guarantees buf free
    if (sub < 2) issue(sub + 2);    // loads stay in flight across bar_lds

    if constexpr (!MAXOUT) {
      const u16* ap = xs[cur] + (wv * 16 + lr) * PITCH + quad * 8;
      floatx4 acc[4];
      #pragma unroll
      for (int nt = 0; nt < 4; ++nt) acc[nt] = (floatx4){0.f, 0.f, 0.f, 0.f};
      #pragma unroll
      for (int ks = 0; ks < KSTEPS; ++ks) {
        short8 av = ld_frag8(ap + ks * 32);
        #pragma unroll
        for (int nt = 0; nt < 4; ++nt)
          acc[nt] = __builtin_amdgcn_mfma_f32_16x16x32_bf16(av, wf[nt][ks], acc[nt], 0, 0, 0);
      }
      const int R0 = P0 + sub * 64 + wv * 16 + quad * 4;
      #pragma unroll
      for (int nt = 0; nt < 4; ++nt) {
        #pragma unroll
        for (int r = 0; r < 4; ++r) {
          float v = acc[nt][r];
          s1[nt] += v; s2[nt] += v * v;
          float vo = __shfl_xor(v, 1);
          if ((lr & 1) == 0)
            yo[(size_t)(R0 + r) * 32 + nt * 8 + (lr >> 1)] = pk_bf16(v, vo);
        }
      }
    } else {
      // wave = 32 rows (rg) x 64 chans (cg): max-group fully in-wave
      short8 av[2][KSTEPS];
      #pragma unroll
      for (int h = 0; h < 2; ++h)
        #pragma unroll
        for (int ks = 0; ks < KSTEPS; ++ks)
          av[h][ks] = ld_frag8(xs[cur] + (rg * 32 + h * 16 + lr) * PITCH + quad * 8 + ks * 32);
      floatx4 acc[2][4];
      #pragma unroll
      for (int h = 0; h < 2; ++h)
        #pragma unroll
        for (int nt = 0; nt < 4; ++nt) acc[h][nt] = (floatx4){0.f, 0.f, 0.f, 0.f};
      #pragma unroll
      for (int ks = 0; ks < KSTEPS; ++ks)
        #pragma unroll
        for (int nt = 0; nt < 4; ++nt)
          #pragma unroll
          for (int h = 0; h < 2; ++h)
            acc[h][nt] = __builtin_amdgcn_mfma_f32_16x16x32_bf16(av[h][ks], wf[nt][ks], acc[h][nt], 0, 0, 0);
      float mx[4], mn[4];
      #pragma unroll
      for (int nt = 0; nt < 4; ++nt) {
        mx[nt] = -INFINITY; mn[nt] = INFINITY;
        #pragma unroll
        for (int h = 0; h < 2; ++h)
          #pragma unroll
          for (int r = 0; r < 4; ++r) {
            float v = acc[h][nt][r];
            s1[nt] += v; s2[nt] += v * v;
            mx[nt] = fmaxf(mx[nt], v); mn[nt] = fminf(mn[nt], v);
          }
        mx[nt] = fmaxf(mx[nt], __shfl_xor(mx[nt], 16));
        mx[nt] = fmaxf(mx[nt], __shfl_xor(mx[nt], 32));
        mn[nt] = fminf(mn[nt], __shfl_xor(mn[nt], 16));
        mn[nt] = fminf(mn[nt], __shfl_xor(mn[nt], 32));
      }
      if (lane < 16) {
        const int grp = blk * 8 + sub * 2 + rg;   // b*1024 + n2
        #pragma unroll
        for (int nt = 0; nt < 4; ++nt)
          gm[(size_t)grp * 128 + cg * 64 + nt * 16 + lr] = pk_bf16(mx[nt], mn[nt]);
      }
    }
    if (sub < 3) bar_lds();   // LDS-only barrier: vmem stays in flight
  }

  // block stats: shuffle over quads, LDS over waves, single barrier
  #pragma unroll
  for (int nt = 0; nt < 4; ++nt) {
    s1[nt] += __shfl_xor(s1[nt], 16); s1[nt] += __shfl_xor(s1[nt], 32);
    s2[nt] += __shfl_xor(s2[nt], 16); s2[nt] += __shfl_xor(s2[nt], 32);
  }
  if (lane < 16) {
    #pragma unroll
    for (int nt = 0; nt < 4; ++nt) {
      red[wv * 64 + nt * 16 + lr] = s1[nt];
      red[256 + wv * 64 + nt * 16 + lr] = s2[nt];
    }
  }
  __syncthreads();
  if constexpr (!MAXOUT) {
    if (t < 64) {
      partial[(size_t)blk * 128 + t] = red[t] + red[64 + t] + red[128 + t] + red[192 + t];
    } else if (t < 128) {
      int c = t - 64;
      partial[(size_t)blk * 128 + t] = red[256 + c] + red[320 + c] + red[384 + c] + red[448 + c];
    }
  } else {
    if (t < 128) {
      int half = t >> 6, i = t & 63;
      partial[(size_t)blk * 256 + t] = red[half * 64 + i] + red[(half + 2) * 64 + i];
    } else {
      int c = t - 128, half = c >> 6, i = c & 63;
      partial[(size_t)blk * 256 + t] = red[256 + half * 64 + i] + red[256 + (half + 2) * 64 + i];
    }
  }
}

// ---- merged stats: 64 blocks; atomic accumulate; last block finalizes scale/shift ----
__global__ __launch_bounds__(256) void bn_stats(const float* __restrict__ partial,
                                                float* __restrict__ accv,
                                                const float* __restrict__ gam,
                                                const float* __restrict__ bet,
                                                float* __restrict__ ssout,
                                                u32* __restrict__ counter, int och) {
  __shared__ float l[256];
  __shared__ u32 rank;
  const int cols = 2 * och, t = threadIdx.x;
  if (t < cols) {
    const size_t r0 = (size_t)blockIdx.x * 32;
    float s = 0.f;
    for (int r = 0; r < 32; ++r) s += partial[(r0 + r) * cols + t];
    atomicAdd(&accv[t], s);
  }
  __threadfence();
  __syncthreads();
  if (t == 0) rank = atomicAdd(counter, 1u);
  __syncthreads();
  if (rank != 63) return;
  __threadfence();
  if (t < cols) l[t] = accv[t];
  __syncthreads();
  if (t < och) {
    const float invN = 1.f / (float)NPTS;
    float mean = l[t] * invN;
    float var  = fmaxf(l[och + t] * invN - mean * mean, 0.f);
    float scale = gam[t] * rsqrtf(var + 1e-5f);
    ssout[t] = scale;
    ssout[och + t] = bet[t] - mean * scale;
  }
}

// ---- final: BN2 + relu on packed max/min, transpose to [b][c][n2] ----
__global__ __launch_bounds__(256) void final_out(const u32* __restrict__ gm,
                                                 const float* __restrict__ ss2,
                                                 float* __restrict__ out) {
  __shared__ float tile[64 * 33];
  int blk = blockIdx.x;                 // 1024 = 16 * 4 * 16
  int b = blk >> 6, rem = blk & 63, cc = rem >> 4, nn = rem & 15;
  int t = threadIdx.x;
  #pragma unroll
  for (int i = 0; i < 8; ++i) {
    int flat = t + i * 256;             // 2048
    int n2l = flat >> 5, cl = flat & 31;
    int c = cc * 32 + cl;
    size_t idx = (size_t)((b << 10) + nn * 64 + n2l) * 128 + c;
    u32 p = gm[idx];
    float mx = b2f((u16)(p & 0xffffu)), mn = b2f((u16)(p >> 16));
    float scv = ss2[c], shv = ss2[128 + c];
    float v = (scv >= 0.f) ? mx : mn;
    tile[n2l * 33 + cl] = fmaxf(scv * v + shv, 0.f);
  }
  __syncthreads();
  #pragma unroll
  for (int i = 0; i < 8; ++i) {
    int flat = t + i * 256;
    int cl = flat >> 6, n2l = flat & 63;
    out[(size_t)((b * 128) + cc * 32 + cl) * 1024 + nn * 64 + n2l] = tile[n2l * 33 + cl];
  }
}

extern "C" void kernel_launch(void* const* d_in, const int* in_sizes, int n_in,
                              void* d_out, int out_size, void* d_ws, size_t ws_size,
                              hipStream_t stream) {
  const float* in_xyz  = (const float*)d_in[0];
  const float* out_xyz = (const float*)d_in[1];
  const float* in_feat = (const float*)d_in[2];
  const int*   nbr     = (const int*)d_in[3];
  const float* W0 = (const float*)d_in[4];
  const float* g0 = (const float*)d_in[5];
  const float* b0 = (const float*)d_in[6];
  const float* W1 = (const float*)d_in[7];
  const float* g1 = (const float*)d_in[8];
  const float* b1 = (const float*)d_in[9];
  const float* W2 = (const float*)d_in[10];
  const float* g2 = (const float*)d_in[11];
  const float* b2 = (const float*)d_in[12];
  float* out = (float*)d_out;

  char* ws = (char*)d_ws;
  float*  ssbuf = (float*)(ws + 0);            // 768 f32
  u32*    cnt   = (u32*)(ws + 3072);           // 4 u32
  float*  accv  = (float*)(ws + 3584);         // 512 f32 (zones: +0 /+128 /+256)
  u16*    Wb    = (u16*)(ws + 8192);           // 20480 u16
  u16*    featT = (u16*)(ws + 262144);         // 8 MiB
  uint2*  dxyz  = (uint2*)(ws + 8650752);      // 4 MiB
  u16*    y0    = (u16*)(ws + 13631488);       // 64 MiB
  u16*    y1    = (u16*)(ws + 80740352);       // 64 MiB (end 147,849,216)
  // aliased into dead regions:
  float*  p0    = (float*)(ws + 80740352);     // y1 area; consumed before y1 written
  float*  p1    = (float*)(ws + 262144);       // featT area; featT dead after L0
  u32*    gm    = (u32*)(ws + 13631488);       // y0 area; y0 dead after L1 (8 MiB packed)
  float*  p2    = (float*)(ws + 13631488 + 8388608);         // 2 MiB

  hipLaunchKernelGGL(prep_all, dim3(6224), dim3(256), 0, stream,
                     in_feat, in_xyz, out_xyz, nbr, W0, W1, W2, featT, dxyz, Wb, cnt, accv);

  hipLaunchKernelGGL((gemm_layer<3, 64, true, false>), dim3(2048), dim3(256), 0, stream,
                     featT, dxyz, nbr, Wb, nullptr, y0, nullptr, p0);
  hipLaunchKernelGGL(bn_stats, dim3(64), dim3(256), 0, stream,
                     p0, accv, g0, b0, ssbuf, cnt, 64);

  hipLaunchKernelGGL((gemm_layer<2, 64, false, false>), dim3(2048), dim3(256), 0, stream,
                     y0, nullptr, nullptr, Wb + 6656, ssbuf, y1, nullptr, p1);
  hipLaunchKernelGGL(bn_stats, dim3(64), dim3(256), 0, stream,
                     p1, accv + 128, g1, b1, ssbuf + 256, cnt + 1, 64);

  hipLaunchKernelGGL((gemm_layer<2, 128, false, true>), dim3(2048), dim3(256), 0, stream,
                     y1, nullptr, nullptr, Wb + 11264, ssbuf + 256, nullptr, gm, p2);
  hipLaunchKernelGGL(bn_stats, dim3(64), dim3(256), 0, stream,
                     p2, accv + 256, g2, b2, ssbuf + 512, cnt + 2, 128);

  hipLaunchKernelGGL(final_out, dim3(1024), dim3(256), 0, stream, gm, ssbuf + 512, out);
}

// Round 12
// 213.856 us; speedup vs baseline: 1.1879x; 1.0014x over previous
//
#include <hip/hip_runtime.h>
#include <cstdint>

typedef unsigned short u16;
typedef unsigned int   u32;
typedef __attribute__((ext_vector_type(8))) short  short8;
typedef __attribute__((ext_vector_type(4))) float  floatx4;

#define NPTS 524288   // B*N2*K

__device__ __forceinline__ float b2f(u16 h) { return __uint_as_float(((u32)h) << 16); }
__device__ __forceinline__ u16 f2b(float f) {
  u32 u = __float_as_uint(f);
  return (u16)((u + 0x7FFFu + ((u >> 16) & 1u)) >> 16);
}
__device__ __forceinline__ u32 pk_bf16(float lo, float hi) {
  return (u32)f2b(lo) | ((u32)f2b(hi) << 16);
}
__device__ __forceinline__ short8 ld_frag8(const u16* p) {
  union { uint4 q; short8 s; } x;
  x.q = *(const uint4*)p;
  return x.s;
}
// barrier that drains ONLY LDS ops — global loads/stores stay in flight
__device__ __forceinline__ void bar_lds() {
  asm volatile("s_waitcnt lgkmcnt(0)\n\ts_barrier" ::: "memory");
}

// ---- prep: W -> bf16, all pitch 72; W0f = W0[:,0:64] only (xyz cols handled separately) ----
// Wb: W0f 64x72 @0 ; W1 64x72 @4608 ; W2 128x72 @9216  (18432 u16)
__global__ __launch_bounds__(256) void prep_all(const float* __restrict__ W0,
                                                const float* __restrict__ W1,
                                                const float* __restrict__ W2,
                                                u16* __restrict__ Wb,
                                                u32* __restrict__ cnt,
                                                float* __restrict__ accz) {
  const int bk = blockIdx.x, t = threadIdx.x;
  int s = bk * 256 + t;   // < 18432
  u16 v = 0;
  if (s < 4608)      { int o = s / 72, c = s % 72; if (c < 64) v = f2b(W0[o * 67 + c]); }
  else if (s < 9216) { int q = s - 4608; int o = q / 72, c = q % 72; if (c < 64) v = f2b(W1[o * 64 + c]); }
  else               { int q = s - 9216; int o = q / 72, c = q % 72; if (c < 64) v = f2b(W2[o * 64 + c]); }
  Wb[s] = v;
  if (bk == 0) {
    if (t < 4) cnt[t] = 0u;
    accz[t] = 0.f;
    accz[256 + t] = 0.f;
  }
}

// ---- zgemm: z[b][n][64] = W0f · in_feature[b][:][n]  (dense, 1024 blocks x 64 rows) ----
__global__ __launch_bounds__(256) void zgemm(const float* __restrict__ inf,
                                             const u16* __restrict__ Wb,
                                             u16* __restrict__ z) {
  const int t = threadIdx.x, blk = blockIdx.x;
  const int lane = t & 63, wv = t >> 6, lr = lane & 15, quad = lane >> 4;
  const int b = blk >> 6, n0 = (blk & 63) * 64;

  short8 wf[4][2];
  #pragma unroll
  for (int nt = 0; nt < 4; ++nt) {
    const u16* wr = Wb + (nt * 16 + lr) * 72 + quad * 8;
    #pragma unroll
    for (int ks = 0; ks < 2; ++ks) wf[nt][ks] = ld_frag8(wr + ks * 32);
  }

  // A fragment: rows n = n0+wv*16+lr, k = ks*32+quad*8+j ; columnar f32 loads
  const float* fb = inf + (size_t)b * 262144 + (n0 + wv * 16 + lr);
  short8 av[2];
  #pragma unroll
  for (int ks = 0; ks < 2; ++ks) {
    union { u32 u[4]; short8 s; } a;
    #pragma unroll
    for (int j = 0; j < 4; ++j) {
      int c0 = ks * 32 + quad * 8 + 2 * j;
      a.u[j] = pk_bf16(fb[(size_t)c0 * 4096], fb[(size_t)(c0 + 1) * 4096]);
    }
    av[ks] = a.s;
  }

  floatx4 acc[4];
  #pragma unroll
  for (int nt = 0; nt < 4; ++nt) acc[nt] = (floatx4){0.f, 0.f, 0.f, 0.f};
  #pragma unroll
  for (int ks = 0; ks < 2; ++ks)
    #pragma unroll
    for (int nt = 0; nt < 4; ++nt)
      acc[nt] = __builtin_amdgcn_mfma_f32_16x16x32_bf16(av[ks], wf[nt][ks], acc[nt], 0, 0, 0);

  u32* zo = (u32*)z;
  const int R0 = b * 4096 + n0 + wv * 16 + quad * 4;
  #pragma unroll
  for (int nt = 0; nt < 4; ++nt) {
    #pragma unroll
    for (int r = 0; r < 4; ++r) {
      float v = acc[nt][r];
      float vo = __shfl_xor(v, 1);
      if ((lr & 1) == 0)
        zo[(size_t)(R0 + r) * 32 + nt * 8 + (lr >> 1)] = pk_bf16(v, vo);
    }
  }
}

// ---- gather-add: y0[p] = z[nbr[p]] + W0x·(xyz[nbr[p]]-oxyz[n2]) ; streaming, no barriers ----
__global__ __launch_bounds__(256) void gather_add(const u16* __restrict__ z,
                                                  const float* __restrict__ ixyz,
                                                  const float* __restrict__ oxyz,
                                                  const int* __restrict__ nbr,
                                                  const float* __restrict__ W0,
                                                  u16* __restrict__ y0,
                                                  float* __restrict__ partial) {
  __shared__ float wx[64], wy[64], wz[64];
  __shared__ float red[512];
  const int t = threadIdx.x, blk = blockIdx.x;
  if (t < 64) {
    wx[t] = W0[t * 67 + 64];
    wy[t] = W0[t * 67 + 65];
    wz[t] = W0[t * 67 + 66];
  }
  __syncthreads();
  const int s4 = t & 3;
  const int b = blk >> 7;
  const float* ix = ixyz + (size_t)b * 12288;
  const float* ox = oxyz + (size_t)b * 3072;

  float s1[16], s2[16];
  #pragma unroll
  for (int i = 0; i < 16; ++i) { s1[i] = 0.f; s2[i] = 0.f; }

  int idx[4], n2v[4];
  #pragma unroll
  for (int u = 0; u < 4; ++u) {
    int row = blk * 256 + u * 64 + (t >> 2);
    idx[u] = nbr[row];
    n2v[u] = (row >> 5) & 1023;
  }

  #pragma unroll
  for (int u = 0; u < 4; ++u) {
    const int id = idx[u];
    const u16* zr = z + ((size_t)(b << 12) + id) * 64 + s4 * 16;
    uint4 a0 = *(const uint4*)zr;
    uint4 a1 = *(const uint4*)(zr + 8);
    float dx = ix[id]        - ox[n2v[u]];
    float dy = ix[4096 + id] - ox[1024 + n2v[u]];
    float dzv = ix[8192 + id] - ox[2048 + n2v[u]];
    u32 w[8] = { a0.x, a0.y, a0.z, a0.w, a1.x, a1.y, a1.z, a1.w };
    u32 o[8];
    #pragma unroll
    for (int i = 0; i < 8; ++i) {
      int c = s4 * 16 + 2 * i;
      float lo = b2f((u16)(w[i] & 0xffffu)) + wx[c] * dx + wy[c] * dy + wz[c] * dzv;
      float hi = b2f((u16)(w[i] >> 16)) + wx[c + 1] * dx + wy[c + 1] * dy + wz[c + 1] * dzv;
      s1[2 * i] += lo;     s2[2 * i] += lo * lo;
      s1[2 * i + 1] += hi; s2[2 * i + 1] += hi * hi;
      o[i] = pk_bf16(lo, hi);
    }
    int row = blk * 256 + u * 64 + (t >> 2);
    u16* yrow = y0 + (size_t)row * 64 + s4 * 16;
    *(uint4*)yrow = make_uint4(o[0], o[1], o[2], o[3]);
    *(uint4*)(yrow + 8) = make_uint4(o[4], o[5], o[6], o[7]);
  }

  // reduce across the 16 m-lanes (stride 4) of each wave
  #pragma unroll
  for (int i = 0; i < 16; ++i) {
    s1[i] += __shfl_xor(s1[i], 4);  s2[i] += __shfl_xor(s2[i], 4);
    s1[i] += __shfl_xor(s1[i], 8);  s2[i] += __shfl_xor(s2[i], 8);
    s1[i] += __shfl_xor(s1[i], 16); s2[i] += __shfl_xor(s2[i], 16);
    s1[i] += __shfl_xor(s1[i], 32); s2[i] += __shfl_xor(s2[i], 32);
  }
  const int wv = t >> 6, lane = t & 63;
  if (lane < 4) {
    #pragma unroll
    for (int i = 0; i < 16; ++i) {
      red[wv * 128 + lane * 16 + i] = s1[i];
      red[wv * 128 + 64 + lane * 16 + i] = s2[i];
    }
  }
  __syncthreads();
  if (t < 128)
    partial[(size_t)blk * 128 + t] = red[t] + red[128 + t] + red[256 + t] + red[384 + t];
}

// ---- L1/L2: 256 rows/block, dbuf LDS x-tile, W in regs, 2-deep issue (KSTEPS=2) ----
template<int OCH, bool MAXOUT>
__global__ __launch_bounds__(256, 4) void gemm_layer(
    const u16* __restrict__ xsrc, const u16* __restrict__ Wb,
    const float* __restrict__ ssin, u16* __restrict__ yout,
    u32* __restrict__ gm, float* __restrict__ partial) {
  constexpr int PITCH = 72;
  __shared__ __align__(16) u16 xs[2][64 * PITCH];
  __shared__ float red[512];
  __shared__ float ss[128];

  const int t = threadIdx.x, blk = blockIdx.x;
  const int lane = t & 63, wv = t >> 6, lr = lane & 15, quad = lane >> 4;
  const int m = t >> 2, s4 = t & 3;
  const int P0 = blk * 256;
  const int rg = wv >> 1, cg = wv & 1;   // MAXOUT wave mapping

  short8 wf[4][2];
  #pragma unroll
  for (int nt = 0; nt < 4; ++nt) {
    const int orow = (MAXOUT ? cg * 64 : 0) + nt * 16 + lr;
    const u16* wr = Wb + orow * PITCH + quad * 8;
    #pragma unroll
    for (int ks = 0; ks < 2; ++ks) wf[nt][ks] = ld_frag8(wr + ks * 32);
  }

  if (t < 128) ss[t] = ssin[t];
  __syncthreads();   // ss visible before commit uses it

  uint4 f0, f1;
  auto issue = [&](int sub) {
    const u16* row = xsrc + ((size_t)(P0 + sub * 64 + m) << 6);
    f0 = *(const uint4*)(row + s4 * 16);
    f1 = *(const uint4*)(row + s4 * 16 + 8);
  };
  auto commit = [&](int bu) {
    u16* xrow = xs[bu] + m * PITCH + s4 * 16;
    u32 w[8] = { f0.x, f0.y, f0.z, f0.w, f1.x, f1.y, f1.z, f1.w };
    u32 o[8];
    #pragma unroll
    for (int i = 0; i < 8; ++i) {
      const int c = s4 * 16 + i * 2;
      float lo = fmaxf(b2f((u16)(w[i] & 0xffffu)) * ss[c]     + ss[64 + c],     0.f);
      float hi = fmaxf(b2f((u16)(w[i] >> 16))     * ss[c + 1] + ss[64 + c + 1], 0.f);
      o[i] = pk_bf16(lo, hi);
    }
    *(uint4*)(xrow + 0) = make_uint4(o[0], o[1], o[2], o[3]);
    *(uint4*)(xrow + 8) = make_uint4(o[4], o[5], o[6], o[7]);
  };

  issue(0); commit(0);
  issue(1);
  __syncthreads();

  float s1[4] = {0.f, 0.f, 0.f, 0.f}, s2[4] = {0.f, 0.f, 0.f, 0.f};
  u32* yo = (u32*)yout;

  for (int sub = 0; sub < 4; ++sub) {
    const int cur = sub & 1;
    if (sub < 3) commit(cur ^ 1);
    if (sub < 2) issue(sub + 2);

    if constexpr (!MAXOUT) {
      const u16* ap = xs[cur] + (wv * 16 + lr) * PITCH + quad * 8;
      floatx4 acc[4];
      #pragma unroll
      for (int nt = 0; nt < 4; ++nt) acc[nt] = (floatx4){0.f, 0.f, 0.f, 0.f};
      #pragma unroll
      for (int ks = 0; ks < 2; ++ks) {
        short8 av = ld_frag8(ap + ks * 32);
        #pragma unroll
        for (int nt = 0; nt < 4; ++nt)
          acc[nt] = __builtin_amdgcn_mfma_f32_16x16x32_bf16(av, wf[nt][ks], acc[nt], 0, 0, 0);
      }
      const int R0 = P0 + sub * 64 + wv * 16 + quad * 4;
      #pragma unroll
      for (int nt = 0; nt < 4; ++nt) {
        #pragma unroll
        for (int r = 0; r < 4; ++r) {
          float v = acc[nt][r];
          s1[nt] += v; s2[nt] += v * v;
          float vo = __shfl_xor(v, 1);
          if ((lr & 1) == 0)
            yo[(size_t)(R0 + r) * 32 + nt * 8 + (lr >> 1)] = pk_bf16(v, vo);
        }
      }
    } else {
      short8 av[2][2];
      #pragma unroll
      for (int h = 0; h < 2; ++h)
        #pragma unroll
        for (int ks = 0; ks < 2; ++ks)
          av[h][ks] = ld_frag8(xs[cur] + (rg * 32 + h * 16 + lr) * PITCH + quad * 8 + ks * 32);
      floatx4 acc[2][4];
      #pragma unroll
      for (int h = 0; h < 2; ++h)
        #pragma unroll
        for (int nt = 0; nt < 4; ++nt) acc[h][nt] = (floatx4){0.f, 0.f, 0.f, 0.f};
      #pragma unroll
      for (int ks = 0; ks < 2; ++ks)
        #pragma unroll
        for (int nt = 0; nt < 4; ++nt)
          #pragma unroll
          for (int h = 0; h < 2; ++h)
            acc[h][nt] = __builtin_amdgcn_mfma_f32_16x16x32_bf16(av[h][ks], wf[nt][ks], acc[h][nt], 0, 0, 0);
      float mx[4], mn[4];
      #pragma unroll
      for (int nt = 0; nt < 4; ++nt) {
        mx[nt] = -INFINITY; mn[nt] = INFINITY;
        #pragma unroll
        for (int h = 0; h < 2; ++h)
          #pragma unroll
          for (int r = 0; r < 4; ++r) {
            float v = acc[h][nt][r];
            s1[nt] += v; s2[nt] += v * v;
            mx[nt] = fmaxf(mx[nt], v); mn[nt] = fminf(mn[nt], v);
          }
        mx[nt] = fmaxf(mx[nt], __shfl_xor(mx[nt], 16));
        mx[nt] = fmaxf(mx[nt], __shfl_xor(mx[nt], 32));
        mn[nt] = fminf(mn[nt], __shfl_xor(mn[nt], 16));
        mn[nt] = fminf(mn[nt], __shfl_xor(mn[nt], 32));
      }
      if (lane < 16) {
        const int grp = blk * 8 + sub * 2 + rg;
        #pragma unroll
        for (int nt = 0; nt < 4; ++nt)
          gm[(size_t)grp * 128 + cg * 64 + nt * 16 + lr] = pk_bf16(mx[nt], mn[nt]);
      }
    }
    if (sub < 3) bar_lds();
  }

  #pragma unroll
  for (int nt = 0; nt < 4; ++nt) {
    s1[nt] += __shfl_xor(s1[nt], 16); s1[nt] += __shfl_xor(s1[nt], 32);
    s2[nt] += __shfl_xor(s2[nt], 16); s2[nt] += __shfl_xor(s2[nt], 32);
  }
  if (lane < 16) {
    #pragma unroll
    for (int nt = 0; nt < 4; ++nt) {
      red[wv * 64 + nt * 16 + lr] = s1[nt];
      red[256 + wv * 64 + nt * 16 + lr] = s2[nt];
    }
  }
  __syncthreads();
  if constexpr (!MAXOUT) {
    if (t < 64) {
      partial[(size_t)blk * 128 + t] = red[t] + red[64 + t] + red[128 + t] + red[192 + t];
    } else if (t < 128) {
      int c = t - 64;
      partial[(size_t)blk * 128 + t] = red[256 + c] + red[320 + c] + red[384 + c] + red[448 + c];
    }
  } else {
    if (t < 128) {
      int half = t >> 6, i = t & 63;
      partial[(size_t)blk * 256 + t] = red[half * 64 + i] + red[(half + 2) * 64 + i];
    } else {
      int c = t - 128, half = c >> 6, i = c & 63;
      partial[(size_t)blk * 256 + t] = red[256 + half * 64 + i] + red[256 + (half + 2) * 64 + i];
    }
  }
}

// ---- merged stats: 64 blocks; atomic accumulate; last block finalizes scale/shift ----
__global__ __launch_bounds__(256) void bn_stats(const float* __restrict__ partial,
                                                float* __restrict__ accv,
                                                const float* __restrict__ gam,
                                                const float* __restrict__ bet,
                                                float* __restrict__ ssout,
                                                u32* __restrict__ counter, int och) {
  __shared__ float l[256];
  __shared__ u32 rank;
  const int cols = 2 * och, t = threadIdx.x;
  if (t < cols) {
    const size_t r0 = (size_t)blockIdx.x * 32;
    float s = 0.f;
    for (int r = 0; r < 32; ++r) s += partial[(r0 + r) * cols + t];
    atomicAdd(&accv[t], s);
  }
  __threadfence();
  __syncthreads();
  if (t == 0) rank = atomicAdd(counter, 1u);
  __syncthreads();
  if (rank != 63) return;
  __threadfence();
  if (t < cols) l[t] = accv[t];
  __syncthreads();
  if (t < och) {
    const float invN = 1.f / (float)NPTS;
    float mean = l[t] * invN;
    float var  = fmaxf(l[och + t] * invN - mean * mean, 0.f);
    float scale = gam[t] * rsqrtf(var + 1e-5f);
    ssout[t] = scale;
    ssout[och + t] = bet[t] - mean * scale;
  }
}

// ---- final: BN2 + relu on packed max/min, transpose to [b][c][n2] ----
__global__ __launch_bounds__(256) void final_out(const u32* __restrict__ gm,
                                                 const float* __restrict__ ss2,
                                                 float* __restrict__ out) {
  __shared__ float tile[64 * 33];
  int blk = blockIdx.x;
  int b = blk >> 6, rem = blk & 63, cc = rem >> 4, nn = rem & 15;
  int t = threadIdx.x;
  #pragma unroll
  for (int i = 0; i < 8; ++i) {
    int flat = t + i * 256;
    int n2l = flat >> 5, cl = flat & 31;
    int c = cc * 32 + cl;
    size_t idx = (size_t)((b << 10) + nn * 64 + n2l) * 128 + c;
    u32 p = gm[idx];
    float mx = b2f((u16)(p & 0xffffu)), mn = b2f((u16)(p >> 16));
    float scv = ss2[c], shv = ss2[128 + c];
    float v = (scv >= 0.f) ? mx : mn;
    tile[n2l * 33 + cl] = fmaxf(scv * v + shv, 0.f);
  }
  __syncthreads();
  #pragma unroll
  for (int i = 0; i < 8; ++i) {
    int flat = t + i * 256;
    int cl = flat >> 6, n2l = flat & 63;
    out[(size_t)((b * 128) + cc * 32 + cl) * 1024 + nn * 64 + n2l] = tile[n2l * 33 + cl];
  }
}

extern "C" void kernel_launch(void* const* d_in, const int* in_sizes, int n_in,
                              void* d_out, int out_size, void* d_ws, size_t ws_size,
                              hipStream_t stream) {
  const float* in_xyz  = (const float*)d_in[0];
  const float* out_xyz = (const float*)d_in[1];
  const float* in_feat = (const float*)d_in[2];
  const int*   nbr     = (const int*)d_in[3];
  const float* W0 = (const float*)d_in[4];
  const float* g0 = (const float*)d_in[5];
  const float* b0 = (const float*)d_in[6];
  const float* W1 = (const float*)d_in[7];
  const float* g1 = (const float*)d_in[8];
  const float* b1 = (const float*)d_in[9];
  const float* W2 = (const float*)d_in[10];
  const float* g2 = (const float*)d_in[11];
  const float* b2 = (const float*)d_in[12];
  float* out = (float*)d_out;

  char* ws = (char*)d_ws;
  float*  ssbuf = (float*)(ws + 0);            // 768 f32
  u32*    cnt   = (u32*)(ws + 3072);           // 4 u32
  float*  accv  = (float*)(ws + 3584);         // 512 f32 (zones: +0 /+128 /+256)
  u16*    Wb    = (u16*)(ws + 8192);           // 18432 u16
  u16*    z     = (u16*)(ws + 262144);         // 8 MiB  (end 8,650,752)
  u16*    y0    = (u16*)(ws + 8650752);        // 64 MiB (end 75,759,616)
  u16*    y1    = (u16*)(ws + 75759616);       // 64 MiB (end 142,868,480)
  // aliased into dead regions:
  float*  p0    = (float*)(ws + 75759616);     // y1 area; consumed before y1 written
  float*  p1    = (float*)(ws + 262144);       // z area; z dead after gather_add
  u32*    gm    = (u32*)(ws + 8650752);        // y0 area; y0 dead after L1 (8 MiB packed)
  float*  p2    = (float*)(ws + 8650752 + 8388608);          // 2 MiB

  hipLaunchKernelGGL(prep_all, dim3(72), dim3(256), 0, stream, W0, W1, W2, Wb, cnt, accv);

  hipLaunchKernelGGL(zgemm, dim3(1024), dim3(256), 0, stream, in_feat, Wb, z);
  hipLaunchKernelGGL(gather_add, dim3(2048), dim3(256), 0, stream,
                     z, in_xyz, out_xyz, nbr, W0, y0, p0);
  hipLaunchKernelGGL(bn_stats, dim3(64), dim3(256), 0, stream,
                     p0, accv, g0, b0, ssbuf, cnt, 64);

  hipLaunchKernelGGL((gemm_layer<64, false>), dim3(2048), dim3(256), 0, stream,
                     y0, Wb + 4608, ssbuf, y1, nullptr, p1);
  hipLaunchKernelGGL(bn_stats, dim3(64), dim3(256), 0, stream,
                     p1, accv + 128, g1, b1, ssbuf + 256, cnt + 1, 64);

  hipLaunchKernelGGL((gemm_layer<128, true>), dim3(2048), dim3(256), 0, stream,
                     y1, Wb + 9216, ssbuf + 256, nullptr, gm, p2);
  hipLaunchKernelGGL(bn_stats, dim3(64), dim3(256), 0, stream,
                     p2, accv + 256, g2, b2, ssbuf + 512, cnt + 2, 128);

  hipLaunchKernelGGL(final_out, dim3(1024), dim3(256), 0, stream, gm, ssbuf + 512, out);
}

// Round 13
// 211.963 us; speedup vs baseline: 1.1985x; 1.0089x over previous
//
#include <hip/hip_runtime.h>
#include <cstdint>

typedef unsigned short u16;
typedef unsigned int   u32;
typedef __attribute__((ext_vector_type(8))) short  short8;
typedef __attribute__((ext_vector_type(4))) float  floatx4;

#define NPTS 524288   // B*N2*K

__device__ __forceinline__ float b2f(u16 h) { return __uint_as_float(((u32)h) << 16); }
__device__ __forceinline__ u16 f2b(float f) {
  u32 u = __float_as_uint(f);
  return (u16)((u + 0x7FFFu + ((u >> 16) & 1u)) >> 16);
}
__device__ __forceinline__ u32 pk_bf16(float lo, float hi) {
  return (u32)f2b(lo) | ((u32)f2b(hi) << 16);
}
__device__ __forceinline__ short8 ld_frag8(const u16* p) {
  union { uint4 q; short8 s; } x;
  x.q = *(const uint4*)p;
  return x.s;
}
// barrier that drains ONLY LDS ops — global loads/stores stay in flight
__device__ __forceinline__ void bar_lds() {
  asm volatile("s_waitcnt lgkmcnt(0)\n\ts_barrier" ::: "memory");
}

// ---- prep: W -> bf16, all pitch 72; W0f = W0[:,0:64] only (xyz cols handled separately) ----
// Wb: W0f 64x72 @0 ; W1 64x72 @4608 ; W2 128x72 @9216  (18432 u16)
__global__ __launch_bounds__(256) void prep_all(const float* __restrict__ W0,
                                                const float* __restrict__ W1,
                                                const float* __restrict__ W2,
                                                u16* __restrict__ Wb,
                                                u32* __restrict__ cnt,
                                                float* __restrict__ accz) {
  const int bk = blockIdx.x, t = threadIdx.x;
  int s = bk * 256 + t;   // < 18432
  u16 v = 0;
  if (s < 4608)      { int o = s / 72, c = s % 72; if (c < 64) v = f2b(W0[o * 67 + c]); }
  else if (s < 9216) { int q = s - 4608; int o = q / 72, c = q % 72; if (c < 64) v = f2b(W1[o * 64 + c]); }
  else               { int q = s - 9216; int o = q / 72, c = q % 72; if (c < 64) v = f2b(W2[o * 64 + c]); }
  Wb[s] = v;
  if (bk == 0) {
    if (t < 4) cnt[t] = 0u;
    accz[t] = 0.f;
    accz[256 + t] = 0.f;
  }
}

// ---- zgemm: z[b][n][64] = W0f · in_feature[b][:][n]  (dense, 1024 blocks x 64 rows) ----
__global__ __launch_bounds__(256) void zgemm(const float* __restrict__ inf,
                                             const u16* __restrict__ Wb,
                                             u16* __restrict__ z) {
  const int t = threadIdx.x, blk = blockIdx.x;
  const int lane = t & 63, wv = t >> 6, lr = lane & 15, quad = lane >> 4;
  const int b = blk >> 6, n0 = (blk & 63) * 64;

  short8 wf[4][2];
  #pragma unroll
  for (int nt = 0; nt < 4; ++nt) {
    const u16* wr = Wb + (nt * 16 + lr) * 72 + quad * 8;
    #pragma unroll
    for (int ks = 0; ks < 2; ++ks) wf[nt][ks] = ld_frag8(wr + ks * 32);
  }

  const float* fb = inf + (size_t)b * 262144 + (n0 + wv * 16 + lr);
  short8 av[2];
  #pragma unroll
  for (int ks = 0; ks < 2; ++ks) {
    union { u32 u[4]; short8 s; } a;
    #pragma unroll
    for (int j = 0; j < 4; ++j) {
      int c0 = ks * 32 + quad * 8 + 2 * j;
      a.u[j] = pk_bf16(fb[(size_t)c0 * 4096], fb[(size_t)(c0 + 1) * 4096]);
    }
    av[ks] = a.s;
  }

  floatx4 acc[4];
  #pragma unroll
  for (int nt = 0; nt < 4; ++nt) acc[nt] = (floatx4){0.f, 0.f, 0.f, 0.f};
  #pragma unroll
  for (int ks = 0; ks < 2; ++ks)
    #pragma unroll
    for (int nt = 0; nt < 4; ++nt)
      acc[nt] = __builtin_amdgcn_mfma_f32_16x16x32_bf16(av[ks], wf[nt][ks], acc[nt], 0, 0, 0);

  u32* zo = (u32*)z;
  const int R0 = b * 4096 + n0 + wv * 16 + quad * 4;
  #pragma unroll
  for (int nt = 0; nt < 4; ++nt) {
    #pragma unroll
    for (int r = 0; r < 4; ++r) {
      float v = acc[nt][r];
      float vo = __shfl_xor(v, 1);
      if ((lr & 1) == 0)
        zo[(size_t)(R0 + r) * 32 + nt * 8 + (lr >> 1)] = pk_bf16(v, vo);
    }
  }
}

// ---- gather-add: y0[p] = z[nbr[p]] + W0x·(xyz[nbr[p]]-oxyz[n2]) ----
// all loads issued up front (4 gathers in flight/thread), then pure compute
__global__ __launch_bounds__(256) void gather_add(const u16* __restrict__ z,
                                                  const float* __restrict__ ixyz,
                                                  const float* __restrict__ oxyz,
                                                  const int* __restrict__ nbr,
                                                  const float* __restrict__ W0,
                                                  u16* __restrict__ y0,
                                                  float* __restrict__ partial) {
  __shared__ float wx[64], wy[64], wz[64];
  __shared__ float red[512];
  const int t = threadIdx.x, blk = blockIdx.x;
  if (t < 64) {
    wx[t] = W0[t * 67 + 64];
    wy[t] = W0[t * 67 + 65];
    wz[t] = W0[t * 67 + 66];
  }
  __syncthreads();
  const int s4 = t & 3;
  const int b = blk >> 7;
  const float* ix = ixyz + (size_t)b * 12288;
  const float* ox = oxyz + (size_t)b * 3072;

  int idx[4];
  #pragma unroll
  for (int u = 0; u < 4; ++u) idx[u] = nbr[blk * 256 + u * 64 + (t >> 2)];

  // stage ALL loads
  uint4 a0[4], a1[4];
  float dx[4], dy[4], dzv[4];
  #pragma unroll
  for (int u = 0; u < 4; ++u) {
    const int id = idx[u];
    const u16* zr = z + ((size_t)(b << 12) + id) * 64 + s4 * 16;
    a0[u] = *(const uint4*)zr;
    a1[u] = *(const uint4*)(zr + 8);
    const int n2 = ((blk * 256 + u * 64 + (t >> 2)) >> 5) & 1023;
    dx[u]  = ix[id]        - ox[n2];
    dy[u]  = ix[4096 + id] - ox[1024 + n2];
    dzv[u] = ix[8192 + id] - ox[2048 + n2];
  }

  float s1[16], s2[16];
  #pragma unroll
  for (int i = 0; i < 16; ++i) { s1[i] = 0.f; s2[i] = 0.f; }

  #pragma unroll
  for (int u = 0; u < 4; ++u) {
    u32 w[8] = { a0[u].x, a0[u].y, a0[u].z, a0[u].w, a1[u].x, a1[u].y, a1[u].z, a1[u].w };
    u32 o[8];
    #pragma unroll
    for (int i = 0; i < 8; ++i) {
      int c = s4 * 16 + 2 * i;
      float lo = b2f((u16)(w[i] & 0xffffu)) + wx[c] * dx[u] + wy[c] * dy[u] + wz[c] * dzv[u];
      float hi = b2f((u16)(w[i] >> 16)) + wx[c + 1] * dx[u] + wy[c + 1] * dy[u] + wz[c + 1] * dzv[u];
      s1[2 * i] += lo;     s2[2 * i] += lo * lo;
      s1[2 * i + 1] += hi; s2[2 * i + 1] += hi * hi;
      o[i] = pk_bf16(lo, hi);
    }
    int row = blk * 256 + u * 64 + (t >> 2);
    u16* yrow = y0 + (size_t)row * 64 + s4 * 16;
    *(uint4*)yrow = make_uint4(o[0], o[1], o[2], o[3]);
    *(uint4*)(yrow + 8) = make_uint4(o[4], o[5], o[6], o[7]);
  }

  #pragma unroll
  for (int i = 0; i < 16; ++i) {
    s1[i] += __shfl_xor(s1[i], 4);  s2[i] += __shfl_xor(s2[i], 4);
    s1[i] += __shfl_xor(s1[i], 8);  s2[i] += __shfl_xor(s2[i], 8);
    s1[i] += __shfl_xor(s1[i], 16); s2[i] += __shfl_xor(s2[i], 16);
    s1[i] += __shfl_xor(s1[i], 32); s2[i] += __shfl_xor(s2[i], 32);
  }
  const int wv = t >> 6, lane = t & 63;
  if (lane < 4) {
    #pragma unroll
    for (int i = 0; i < 16; ++i) {
      red[wv * 128 + lane * 16 + i] = s1[i];
      red[wv * 128 + 64 + lane * 16 + i] = s2[i];
    }
  }
  __syncthreads();
  if (t < 128)
    partial[(size_t)blk * 128 + t] = red[t] + red[128 + t] + red[256 + t] + red[384 + t];
}

// ---- L1/L2: 512 rows/block (8 subs), dbuf LDS x-tile, W in regs, 2-deep issue ----
template<int OCH, bool MAXOUT>
__global__ __launch_bounds__(256, 4) void gemm_layer(
    const u16* __restrict__ xsrc, const u16* __restrict__ Wb,
    const float* __restrict__ ssin, u16* __restrict__ yout,
    u32* __restrict__ gm, float* __restrict__ partial) {
  constexpr int PITCH = 72;
  constexpr int SUBS = 8;
  __shared__ __align__(16) u16 xs[2][64 * PITCH];
  __shared__ float red[512];
  __shared__ float ss[128];

  const int t = threadIdx.x, blk = blockIdx.x;
  const int lane = t & 63, wv = t >> 6, lr = lane & 15, quad = lane >> 4;
  const int m = t >> 2, s4 = t & 3;
  const int P0 = blk * (SUBS * 64);
  const int rg = wv >> 1, cg = wv & 1;   // MAXOUT wave mapping

  short8 wf[4][2];
  #pragma unroll
  for (int nt = 0; nt < 4; ++nt) {
    const int orow = (MAXOUT ? cg * 64 : 0) + nt * 16 + lr;
    const u16* wr = Wb + orow * PITCH + quad * 8;
    #pragma unroll
    for (int ks = 0; ks < 2; ++ks) wf[nt][ks] = ld_frag8(wr + ks * 32);
  }

  if (t < 128) ss[t] = ssin[t];
  __syncthreads();   // ss visible before commit uses it

  uint4 f0, f1;
  auto issue = [&](int sub) {
    const u16* row = xsrc + ((size_t)(P0 + sub * 64 + m) << 6);
    f0 = *(const uint4*)(row + s4 * 16);
    f1 = *(const uint4*)(row + s4 * 16 + 8);
  };
  auto commit = [&](int bu) {
    u16* xrow = xs[bu] + m * PITCH + s4 * 16;
    u32 w[8] = { f0.x, f0.y, f0.z, f0.w, f1.x, f1.y, f1.z, f1.w };
    u32 o[8];
    #pragma unroll
    for (int i = 0; i < 8; ++i) {
      const int c = s4 * 16 + i * 2;
      float lo = fmaxf(b2f((u16)(w[i] & 0xffffu)) * ss[c]     + ss[64 + c],     0.f);
      float hi = fmaxf(b2f((u16)(w[i] >> 16))     * ss[c + 1] + ss[64 + c + 1], 0.f);
      o[i] = pk_bf16(lo, hi);
    }
    *(uint4*)(xrow + 0) = make_uint4(o[0], o[1], o[2], o[3]);
    *(uint4*)(xrow + 8) = make_uint4(o[4], o[5], o[6], o[7]);
  };

  issue(0); commit(0);
  issue(1);
  __syncthreads();

  float s1[4] = {0.f, 0.f, 0.f, 0.f}, s2[4] = {0.f, 0.f, 0.f, 0.f};
  u32* yo = (u32*)yout;

  for (int sub = 0; sub < SUBS; ++sub) {
    const int cur = sub & 1;
    if (sub < SUBS - 1) commit(cur ^ 1);
    if (sub < SUBS - 2) issue(sub + 2);

    if constexpr (!MAXOUT) {
      const u16* ap = xs[cur] + (wv * 16 + lr) * PITCH + quad * 8;
      floatx4 acc[4];
      #pragma unroll
      for (int nt = 0; nt < 4; ++nt) acc[nt] = (floatx4){0.f, 0.f, 0.f, 0.f};
      #pragma unroll
      for (int ks = 0; ks < 2; ++ks) {
        short8 av = ld_frag8(ap + ks * 32);
        #pragma unroll
        for (int nt = 0; nt < 4; ++nt)
          acc[nt] = __builtin_amdgcn_mfma_f32_16x16x32_bf16(av, wf[nt][ks], acc[nt], 0, 0, 0);
      }
      const int R0 = P0 + sub * 64 + wv * 16 + quad * 4;
      #pragma unroll
      for (int nt = 0; nt < 4; ++nt) {
        #pragma unroll
        for (int r = 0; r < 4; ++r) {
          float v = acc[nt][r];
          s1[nt] += v; s2[nt] += v * v;
          float vo = __shfl_xor(v, 1);
          if ((lr & 1) == 0)
            yo[(size_t)(R0 + r) * 32 + nt * 8 + (lr >> 1)] = pk_bf16(v, vo);
        }
      }
    } else {
      short8 av[2][2];
      #pragma unroll
      for (int h = 0; h < 2; ++h)
        #pragma unroll
        for (int ks = 0; ks < 2; ++ks)
          av[h][ks] = ld_frag8(xs[cur] + (rg * 32 + h * 16 + lr) * PITCH + quad * 8 + ks * 32);
      floatx4 acc[2][4];
      #pragma unroll
      for (int h = 0; h < 2; ++h)
        #pragma unroll
        for (int nt = 0; nt < 4; ++nt) acc[h][nt] = (floatx4){0.f, 0.f, 0.f, 0.f};
      #pragma unroll
      for (int ks = 0; ks < 2; ++ks)
        #pragma unroll
        for (int nt = 0; nt < 4; ++nt)
          #pragma unroll
          for (int h = 0; h < 2; ++h)
            acc[h][nt] = __builtin_amdgcn_mfma_f32_16x16x32_bf16(av[h][ks], wf[nt][ks], acc[h][nt], 0, 0, 0);
      float mx[4], mn[4];
      #pragma unroll
      for (int nt = 0; nt < 4; ++nt) {
        mx[nt] = -INFINITY; mn[nt] = INFINITY;
        #pragma unroll
        for (int h = 0; h < 2; ++h)
          #pragma unroll
          for (int r = 0; r < 4; ++r) {
            float v = acc[h][nt][r];
            s1[nt] += v; s2[nt] += v * v;
            mx[nt] = fmaxf(mx[nt], v); mn[nt] = fminf(mn[nt], v);
          }
        mx[nt] = fmaxf(mx[nt], __shfl_xor(mx[nt], 16));
        mx[nt] = fmaxf(mx[nt], __shfl_xor(mx[nt], 32));
        mn[nt] = fminf(mn[nt], __shfl_xor(mn[nt], 16));
        mn[nt] = fminf(mn[nt], __shfl_xor(mn[nt], 32));
      }
      if (lane < 16) {
        const int grp = blk * (SUBS * 2) + sub * 2 + rg;   // b*1024 + n2
        #pragma unroll
        for (int nt = 0; nt < 4; ++nt)
          gm[(size_t)grp * 128 + cg * 64 + nt * 16 + lr] = pk_bf16(mx[nt], mn[nt]);
      }
    }
    if (sub < SUBS - 1) bar_lds();
  }

  #pragma unroll
  for (int nt = 0; nt < 4; ++nt) {
    s1[nt] += __shfl_xor(s1[nt], 16); s1[nt] += __shfl_xor(s1[nt], 32);
    s2[nt] += __shfl_xor(s2[nt], 16); s2[nt] += __shfl_xor(s2[nt], 32);
  }
  if (lane < 16) {
    #pragma unroll
    for (int nt = 0; nt < 4; ++nt) {
      red[wv * 64 + nt * 16 + lr] = s1[nt];
      red[256 + wv * 64 + nt * 16 + lr] = s2[nt];
    }
  }
  __syncthreads();
  if constexpr (!MAXOUT) {
    if (t < 64) {
      partial[(size_t)blk * 128 + t] = red[t] + red[64 + t] + red[128 + t] + red[192 + t];
    } else if (t < 128) {
      int c = t - 64;
      partial[(size_t)blk * 128 + t] = red[256 + c] + red[320 + c] + red[384 + c] + red[448 + c];
    }
  } else {
    if (t < 128) {
      int half = t >> 6, i = t & 63;
      partial[(size_t)blk * 256 + t] = red[half * 64 + i] + red[(half + 2) * 64 + i];
    } else {
      int c = t - 128, half = c >> 6, i = c & 63;
      partial[(size_t)blk * 256 + t] = red[256 + half * 64 + i] + red[256 + (half + 2) * 64 + i];
    }
  }
}

// ---- merged stats: 64 blocks x `rows`; atomic accumulate; last block finalizes ----
__global__ __launch_bounds__(256) void bn_stats(const float* __restrict__ partial,
                                                float* __restrict__ accv,
                                                const float* __restrict__ gam,
                                                const float* __restrict__ bet,
                                                float* __restrict__ ssout,
                                                u32* __restrict__ counter,
                                                int och, int rows) {
  __shared__ float l[256];
  __shared__ u32 rank;
  const int cols = 2 * och, t = threadIdx.x;
  if (t < cols) {
    const size_t r0 = (size_t)blockIdx.x * rows;
    float s = 0.f;
    for (int r = 0; r < rows; ++r) s += partial[(r0 + r) * cols + t];
    atomicAdd(&accv[t], s);
  }
  __threadfence();
  __syncthreads();
  if (t == 0) rank = atomicAdd(counter, 1u);
  __syncthreads();
  if (rank != 63) return;
  __threadfence();
  if (t < cols) l[t] = accv[t];
  __syncthreads();
  if (t < och) {
    const float invN = 1.f / (float)NPTS;
    float mean = l[t] * invN;
    float var  = fmaxf(l[och + t] * invN - mean * mean, 0.f);
    float scale = gam[t] * rsqrtf(var + 1e-5f);
    ssout[t] = scale;
    ssout[och + t] = bet[t] - mean * scale;
  }
}

// ---- final: BN2 + relu on packed max/min, transpose to [b][c][n2] ----
__global__ __launch_bounds__(256) void final_out(const u32* __restrict__ gm,
                                                 const float* __restrict__ ss2,
                                                 float* __restrict__ out) {
  __shared__ float tile[64 * 33];
  int blk = blockIdx.x;
  int b = blk >> 6, rem = blk & 63, cc = rem >> 4, nn = rem & 15;
  int t = threadIdx.x;
  #pragma unroll
  for (int i = 0; i < 8; ++i) {
    int flat = t + i * 256;
    int n2l = flat >> 5, cl = flat & 31;
    int c = cc * 32 + cl;
    size_t idx = (size_t)((b << 10) + nn * 64 + n2l) * 128 + c;
    u32 p = gm[idx];
    float mx = b2f((u16)(p & 0xffffu)), mn = b2f((u16)(p >> 16));
    float scv = ss2[c], shv = ss2[128 + c];
    float v = (scv >= 0.f) ? mx : mn;
    tile[n2l * 33 + cl] = fmaxf(scv * v + shv, 0.f);
  }
  __syncthreads();
  #pragma unroll
  for (int i = 0; i < 8; ++i) {
    int flat = t + i * 256;
    int cl = flat >> 6, n2l = flat & 63;
    out[(size_t)((b * 128) + cc * 32 + cl) * 1024 + nn * 64 + n2l] = tile[n2l * 33 + cl];
  }
}

extern "C" void kernel_launch(void* const* d_in, const int* in_sizes, int n_in,
                              void* d_out, int out_size, void* d_ws, size_t ws_size,
                              hipStream_t stream) {
  const float* in_xyz  = (const float*)d_in[0];
  const float* out_xyz = (const float*)d_in[1];
  const float* in_feat = (const float*)d_in[2];
  const int*   nbr     = (const int*)d_in[3];
  const float* W0 = (const float*)d_in[4];
  const float* g0 = (const float*)d_in[5];
  const float* b0 = (const float*)d_in[6];
  const float* W1 = (const float*)d_in[7];
  const float* g1 = (const float*)d_in[8];
  const float* b1 = (const float*)d_in[9];
  const float* W2 = (const float*)d_in[10];
  const float* g2 = (const float*)d_in[11];
  const float* b2 = (const float*)d_in[12];
  float* out = (float*)d_out;

  char* ws = (char*)d_ws;
  float*  ssbuf = (float*)(ws + 0);            // 768 f32
  u32*    cnt   = (u32*)(ws + 3072);           // 4 u32
  float*  accv  = (float*)(ws + 3584);         // 512 f32 (zones: +0 /+128 /+256)
  u16*    Wb    = (u16*)(ws + 8192);           // 18432 u16
  u16*    z     = (u16*)(ws + 262144);         // 8 MiB  (end 8,650,752)
  u16*    y0    = (u16*)(ws + 8650752);        // 64 MiB (end 75,759,616)
  u16*    y1    = (u16*)(ws + 75759616);       // 64 MiB (end 142,868,480)
  // aliased into dead regions:
  float*  p0    = (float*)(ws + 75759616);     // y1 area; consumed before y1 written
  float*  p1    = (float*)(ws + 262144);       // z area; z dead after gather_add
  u32*    gm    = (u32*)(ws + 8650752);        // y0 area; y0 dead after L1 (8 MiB packed)
  float*  p2    = (float*)(ws + 8650752 + 8388608);          // 1 MiB

  hipLaunchKernelGGL(prep_all, dim3(72), dim3(256), 0, stream, W0, W1, W2, Wb, cnt, accv);

  hipLaunchKernelGGL(zgemm, dim3(1024), dim3(256), 0, stream, in_feat, Wb, z);
  hipLaunchKernelGGL(gather_add, dim3(2048), dim3(256), 0, stream,
                     z, in_xyz, out_xyz, nbr, W0, y0, p0);
  hipLaunchKernelGGL(bn_stats, dim3(64), dim3(256), 0, stream,
                     p0, accv, g0, b0, ssbuf, cnt, 64, 32);

  hipLaunchKernelGGL((gemm_layer<64, false>), dim3(1024), dim3(256), 0, stream,
                     y0, Wb + 4608, ssbuf, y1, nullptr, p1);
  hipLaunchKernelGGL(bn_stats, dim3(64), dim3(256), 0, stream,
                     p1, accv + 128, g1, b1, ssbuf + 256, cnt + 1, 64, 16);

  hipLaunchKernelGGL((gemm_layer<128, true>), dim3(1024), dim3(256), 0, stream,
                     y1, Wb + 9216, ssbuf + 256, nullptr, gm, p2);
  hipLaunchKernelGGL(bn_stats, dim3(64), dim3(256), 0, stream,
                     p2, accv + 256, g2, b2, ssbuf + 512, cnt + 2, 128, 16);

  hipLaunchKernelGGL(final_out, dim3(1024), dim3(256), 0, stream, gm, ssbuf + 512, out);
}